// Round 4
// baseline (734.634 us; speedup 1.0000x reference)
//
#include <hip/hip_runtime.h>
#include <cstdint>
#include <cstddef>

#define BATCH 16
#define CIN   1024
#define CH    512
#define HW    4096

static constexpr float LN_EPS = 1e-5f;

typedef __bf16 bf16x8 __attribute__((ext_vector_type(8)));
typedef float  f32x4  __attribute__((ext_vector_type(4)));

__device__ __forceinline__ float sigmoidf_(float v) { return 1.0f / (1.0f + __expf(-v)); }

// fp32 -> bf16 bits, round-to-nearest-even
__device__ __forceinline__ unsigned short f2bf(float f) {
    union { float f; uint32_t u; } c; c.f = f;
    uint32_t r = (c.u + 0x7fffu + ((c.u >> 16) & 1u)) >> 16;
    return (unsigned short)r;
}

#define GLOAD_LDS16(g, l)                                                  \
    __builtin_amdgcn_global_load_lds(                                      \
        (const __attribute__((address_space(1))) void*)(g),                \
        (__attribute__((address_space(3))) void*)(l), 16, 0, 0)

// ---------------------------------------------------------------------------
// prep: blocks [0,16384): x[b,c,n] fp32 -> xt[b,n,c] bf16 + fused w_qr dot
//       -> maskpre (atomic).  blocks [16384, 22528): weight convert:
//       wA = [w_ql(512); w_vr(512)] bf16, wB = w_vl(512) bf16.
// ---------------------------------------------------------------------------
__global__ __launch_bounds__(256) void prep_k(
    const float* __restrict__ x, const float* __restrict__ wqr,
    const float* __restrict__ wvr, const float* __restrict__ wql,
    const float* __restrict__ wvl,
    unsigned short* __restrict__ xt, float* __restrict__ maskpre,
    unsigned short* __restrict__ wA, unsigned short* __restrict__ wB)
{
    __shared__ float t[64][65];
    const int tid = threadIdx.x;
    if (blockIdx.x >= 16384) {
        const int j = (blockIdx.x - 16384) * 256 + tid;
        if (j < 1024 * 1024) {
            const int row = j >> 10, col = j & 1023;
            const float v = (row < 512) ? wql[row * 1024 + col]
                                        : wvr[(row - 512) * 1024 + col];
            wA[j] = f2bf(v);
        } else {
            const int k = j - 1024 * 1024;
            wB[k] = f2bf(wvl[k]);
        }
        return;
    }
    const int nb = blockIdx.x & 63;
    const int cb = (blockIdx.x >> 6) & 15;
    const int b  = blockIdx.x >> 10;
    const int c0 = cb * 64;
    const int n0 = nb * 64;
    const int tx = tid & 15, ty = tid >> 4;
    const float* xb = x + ((size_t)b * CIN + c0) * HW + n0;
#pragma unroll
    for (int rr = 0; rr < 4; ++rr) {
        const int row = ty + rr * 16;
        float4 v = *(const float4*)(xb + (size_t)row * HW + tx * 4);
        t[row][tx * 4 + 0] = v.x; t[row][tx * 4 + 1] = v.y;
        t[row][tx * 4 + 2] = v.z; t[row][tx * 4 + 3] = v.w;
    }
    __syncthreads();
    const int n  = tid >> 2;
    const int cp = (tid & 3) * 16;
    __align__(16) unsigned short tmp[16];
    float part = 0.f;
#pragma unroll
    for (int i = 0; i < 16; ++i) {
        const float v = t[cp + i][n];
        tmp[i] = f2bf(v);
        part = fmaf(wqr[c0 + cp + i], v, part);
    }
    unsigned short* dst = xt + ((size_t)b * HW + n0 + n) * CIN + c0 + cp;
    ((uint4*)dst)[0] = ((const uint4*)tmp)[0];
    ((uint4*)dst)[1] = ((const uint4*)tmp)[1];
    part += __shfl_xor(part, 1);
    part += __shfl_xor(part, 2);
    if ((tid & 3) == 0) atomicAdd(&maskpre[(size_t)b * HW + n0 + n], part);
}

// ---------------------------------------------------------------------------
// Persistent-tile 256x256 GEMM, BK=64, 8-phase (T2+T3+T4+T5), 512 thr/8 waves.
// Grid = 256 blocks (1/CU, ONE generation). Block owns (nb = bid&15,
// b = bid>>4) and iterates MT tiles (mt = step>>4) in a FLAT pipeline:
// staging targets step+2 (crossing tile boundaries: A advances 256 rows/tile,
// B panel constant), buffer parity = step&1 continuous, per-tile epilogue
// runs inline while next tile's loads are in flight. Pipeline drains once.
// LDS 128KB: [buf(2)][mat A/B][half(2)] x 16KB. Swizzle: 16B-slot ^= (row&7),
// on BOTH stage-source and read.
// phase 0 (wA = ql|vr, MT=4): ti 0-1 -> gmean += sum_n relu;
//   ti 2-3 -> ctxu += sum_n relu * exp(relu(maskpre[n])) (deferred softmax).
// phase 1 (wB = vl, MT=2): cattnp += sum_m relu * avgx[m].
// ---------------------------------------------------------------------------
__global__ __launch_bounds__(512) void mfma_gemm256(
    const unsigned short* __restrict__ xt,   // [b][n][c] bf16
    const unsigned short* __restrict__ wst,  // weights bf16 [o][c]
    const int MT, const int phase,
    const float* __restrict__ maskp,         // raw maskpre (phase 0)
    const float* __restrict__ avgx,          // phase 1
    float* __restrict__ gmean,
    float* __restrict__ ctx,
    float* __restrict__ cattnp)
{
    const int bid = blockIdx.x;
    const int nb = bid & 15;
    const int b  = bid >> 4;
    const int n0 = nb * 256;

    const int tid  = threadIdx.x;
    const int w    = tid >> 6;
    const int lane = tid & 63;
    const int wm = w >> 2;        // 0..1  (M warp group, 128 rows each)
    const int wn = w & 3;         // 0..3  (N warp group, 64 cols each)
    const int lr = lane & 15;
    const int hi = lane >> 4;
    const int lr7 = lane & 7;

    __shared__ __align__(16) unsigned short lds[2 * 2 * 2 * 8192];  // 128 KiB

    f32x4 acc[8][4];
#pragma unroll
    for (int mi = 0; mi < 8; ++mi)
#pragma unroll
        for (int nj = 0; nj < 4; ++nj) acc[mi][nj] = (f32x4){0.f, 0.f, 0.f, 0.f};

    // ---- staging source pointers (per-lane, inverse-swizzled slot) ----
    const int sr  = lane >> 3;                 // row within 8-row chunk
    const int ssl = (lane & 7) ^ sr;           // swizzled source 16B-slot
    const unsigned short* gA[2][2];            // tile-0 A base (mt added in STG)
    const unsigned short* gB[2][2];
#pragma unroll
    for (int h = 0; h < 2; ++h)
#pragma unroll
        for (int j = 0; j < 2; ++j) {
            const int row = (w * 2 + j) * 8 + sr;
            gA[h][j] = wst + (size_t)(h * 128 + row) * CIN + ssl * 8;
            gB[h][j] = xt + ((size_t)b * HW + n0 + h * 128 + row) * CIN + ssl * 8;
        }

    // stage half-tile (matrix m, half h) for flat step st: tile = st>>4,
    // K-tile = st&15; buffer parity = st&1. LDS dest wave-uniform.
#define STG(m, h, st) do {                                                  \
        const int ti_ = (st) >> 4, k_ = (st) & 15;                          \
        unsigned short* lb_ = lds + ((((st) & 1) * 4) + (m) * 2 + (h)) * 8192 \
                              + (w * 2) * 512;                              \
        const unsigned short* s0_ = (m) ? (gB[h][0] + k_ * 64)              \
                                        : (gA[h][0] + ti_ * (256 * CIN) + k_ * 64); \
        const unsigned short* s1_ = (m) ? (gB[h][1] + k_ * 64)              \
                                        : (gA[h][1] + ti_ * (256 * CIN) + k_ * 64); \
        GLOAD_LDS16(s0_, lb_);                                              \
        GLOAD_LDS16(s1_, lb_ + 512);                                        \
    } while (0)

    // ---- read offsets (shorts), swizzled slot = (s*4+hi) ^ (lr&7) ----
    const int aoff = lr * 64;
    const int boff = (wn & 1) * 4096 + lr * 64;
    const int sl0 = ((0 + hi) ^ lr7) * 8;
    const int sl1 = ((4 + hi) ^ lr7) * 8;

    bf16x8 bf[4][2];

#define PHASE_BODY(q, c, STAGE_STMT, GATE_STMT) do {                        \
        const unsigned short* Ab_ = lds + ((c) * 4 + wm) * 8192;            \
        const unsigned short* Bb_ = lds + ((c) * 4 + 2 + (wn >> 1)) * 8192; \
        if ((q) == 0) {                                                     \
            _Pragma("unroll")                                               \
            for (int nj = 0; nj < 4; ++nj) {                                \
                bf[nj][0] = *(const bf16x8*)(Bb_ + boff + nj * 1024 + sl0); \
                bf[nj][1] = *(const bf16x8*)(Bb_ + boff + nj * 1024 + sl1); \
            }                                                               \
        }                                                                   \
        bf16x8 af_[2][2];                                                   \
        _Pragma("unroll")                                                   \
        for (int mi = 0; mi < 2; ++mi) {                                    \
            af_[mi][0] = *(const bf16x8*)(Ab_ + ((q) * 32 + mi * 16) * 64 + aoff + sl0); \
            af_[mi][1] = *(const bf16x8*)(Ab_ + ((q) * 32 + mi * 16) * 64 + aoff + sl1); \
        }                                                                   \
        STAGE_STMT;                                                         \
        GATE_STMT;                                                          \
        asm volatile("s_barrier" ::: "memory");                             \
        __builtin_amdgcn_s_setprio(1);                                      \
        _Pragma("unroll")                                                   \
        for (int mi = 0; mi < 2; ++mi)                                      \
            _Pragma("unroll")                                               \
            for (int nj = 0; nj < 4; ++nj) {                                \
                acc[(q) * 2 + mi][nj] = __builtin_amdgcn_mfma_f32_16x16x32_bf16( \
                    af_[mi][0], bf[nj][0], acc[(q) * 2 + mi][nj], 0, 0, 0); \
                acc[(q) * 2 + mi][nj] = __builtin_amdgcn_mfma_f32_16x16x32_bf16( \
                    af_[mi][1], bf[nj][1], acc[(q) * 2 + mi][nj], 0, 0, 0); \
            }                                                               \
        __builtin_amdgcn_s_setprio(0);                                      \
        __builtin_amdgcn_sched_barrier(0);                                  \
        asm volatile("s_barrier" ::: "memory");                             \
    } while (0)

    const int T = MT * 16;

    // ---- prologue: step0 {A0,A1,B0,B1}, step1 {B0,B1,A0}; A1(1) in-loop ----
    STG(0, 0, 0); STG(0, 1, 0); STG(1, 0, 0); STG(1, 1, 0);
    STG(1, 0, 1); STG(1, 1, 1); STG(0, 0, 1);
    asm volatile("s_waitcnt vmcnt(6)" ::: "memory");
    asm volatile("s_barrier" ::: "memory");

    const int quad = hi;
#pragma unroll 2
    for (int step = 0; step < T; ++step) {
        const int c = step & 1;
        PHASE_BODY(0, c, { if (step + 1 < T) STG(0, 1, step + 1); }, {});
        PHASE_BODY(1, c, { if (step + 2 < T) STG(1, 0, step + 2); }, {});
        PHASE_BODY(2, c, { if (step + 2 < T) STG(1, 1, step + 2); }, {});
        PHASE_BODY(3, c, { if (step + 2 < T) STG(0, 0, step + 2); },
                   { if (step + 2 < T)       asm volatile("s_waitcnt vmcnt(6)" ::: "memory");
                     else if (step + 2 == T) asm volatile("s_waitcnt vmcnt(0)" ::: "memory"); });

        if ((step & 15) == 15) {
            // ---- inline per-tile epilogue; next tile's loads already in flight.
            // C/D: col = lr, row = wm*128 + mr*16 + quad*4 + reg.
            const int ti = step >> 4;
            if (phase == 0) {
                if (ti < 2) {
                    // gmean[b][o] += sum_n relu
#pragma unroll
                    for (int mr = 0; mr < 8; ++mr)
#pragma unroll
                        for (int r = 0; r < 4; ++r) {
                            float v = 0.f;
#pragma unroll
                            for (int nj = 0; nj < 4; ++nj) v += fmaxf(acc[mr][nj][r], 0.f);
                            v += __shfl_xor(v, 1); v += __shfl_xor(v, 2);
                            v += __shfl_xor(v, 4); v += __shfl_xor(v, 8);
                            if (lr == 0)
                                atomicAdd(&gmean[b * CH + ti * 256 + wm * 128 + mr * 16 + quad * 4 + r], v);
                        }
                } else {
                    // ctxu[b][o] += sum_n relu * exp(relu(maskpre[n]))
                    float ew[4];
#pragma unroll
                    for (int nj = 0; nj < 4; ++nj)
                        ew[nj] = __expf(fmaxf(maskp[(size_t)b * HW + n0 + wn * 64 + nj * 16 + lr], 0.f));
#pragma unroll
                    for (int mr = 0; mr < 8; ++mr)
#pragma unroll
                        for (int r = 0; r < 4; ++r) {
                            float v = 0.f;
#pragma unroll
                            for (int nj = 0; nj < 4; ++nj)
                                v += fmaxf(acc[mr][nj][r], 0.f) * ew[nj];
                            v += __shfl_xor(v, 1); v += __shfl_xor(v, 2);
                            v += __shfl_xor(v, 4); v += __shfl_xor(v, 8);
                            if (lr == 0)
                                atomicAdd(&ctx[b * CH + (ti - 2) * 256 + wm * 128 + mr * 16 + quad * 4 + r], v);
                        }
                }
            } else {
                // cattnp[b][n] += sum_m relu * avgx[m]
                float colsum[4] = {0.f, 0.f, 0.f, 0.f};
#pragma unroll
                for (int mr = 0; mr < 8; ++mr) {
                    float aw[4];
#pragma unroll
                    for (int r = 0; r < 4; ++r)
                        aw[r] = avgx[b * CH + ti * 256 + wm * 128 + mr * 16 + quad * 4 + r];
#pragma unroll
                    for (int nj = 0; nj < 4; ++nj)
#pragma unroll
                        for (int r = 0; r < 4; ++r)
                            colsum[nj] += fmaxf(acc[mr][nj][r], 0.f) * aw[r];
                }
#pragma unroll
                for (int nj = 0; nj < 4; ++nj) {
                    float v = colsum[nj];
                    v += __shfl_xor(v, 16);
                    v += __shfl_xor(v, 32);
                    if (lane < 16)
                        atomicAdd(&cattnp[(size_t)b * HW + n0 + wn * 64 + nj * 16 + lane], v);
                }
            }
            // re-zero accumulators for next tile
#pragma unroll
            for (int mi = 0; mi < 8; ++mi)
#pragma unroll
                for (int nj = 0; nj < 4; ++nj) acc[mi][nj] = (f32x4){0.f, 0.f, 0.f, 0.f};
        }
    }
#undef PHASE_BODY
#undef STG
}

// blocks 0..15: gmean -> /HW -> softmax over 512 ch -> avgx
// blocks 16..31: S[b] = sum_n exp(relu(maskpre[b,n]))  (softmax denominator)
__global__ __launch_bounds__(256) void smch_S_k(const float* __restrict__ gmean,
                                                const float* __restrict__ maskp,
                                                float* __restrict__ avgx,
                                                float* __restrict__ sden)
{
    __shared__ float red[256];
    const int tid = threadIdx.x;
    if (blockIdx.x < 16) {
        const int b = blockIdx.x;
        const float* src = gmean + b * CH;
        float* dst = avgx + b * CH;
        const float v0 = src[tid]       * (1.f / HW);
        const float v1 = src[tid + 256] * (1.f / HW);
        red[tid] = fmaxf(v0, v1); __syncthreads();
        for (int s = 128; s > 0; s >>= 1) { if (tid < s) red[tid] = fmaxf(red[tid], red[tid + s]); __syncthreads(); }
        const float mx = red[0]; __syncthreads();
        const float e0 = __expf(v0 - mx), e1 = __expf(v1 - mx);
        red[tid] = e0 + e1; __syncthreads();
        for (int s = 128; s > 0; s >>= 1) { if (tid < s) red[tid] += red[tid + s]; __syncthreads(); }
        const float inv = 1.f / red[0];
        dst[tid] = e0 * inv; dst[tid + 256] = e1 * inv;
    } else {
        const int b = blockIdx.x - 16;
        const float* row = maskp + (size_t)b * HW;
        float s = 0.f;
        for (int i = tid; i < HW; i += 256) s += __expf(fmaxf(row[i], 0.f));
        red[tid] = s; __syncthreads();
        for (int st = 128; st > 0; st >>= 1) { if (tid < st) red[tid] += red[tid + st]; __syncthreads(); }
        if (tid == 0) sden[b] = red[0];
    }
}

// blocks 0..15: layer_norm(ctxu / S[b]) -> sigmoid -> sattn
// blocks 16..271: cattnp -> sigmoid in place
__global__ __launch_bounds__(256) void lnsig_k(const float* __restrict__ ctx,
                                               const float* __restrict__ sden,
                                               float* __restrict__ sattn,
                                               float* __restrict__ cattnp)
{
    const int tid = threadIdx.x;
    if (blockIdx.x >= 16) {
        const int i = (blockIdx.x - 16) * 256 + tid;
        cattnp[i] = sigmoidf_(cattnp[i]);
        return;
    }
    const int b = blockIdx.x;
    const float invS = 1.f / sden[b];
    const float* src = ctx + b * CH;
    __shared__ float red[256];
    const float v0 = src[tid] * invS, v1 = src[tid + 256] * invS;
    red[tid] = v0 + v1; __syncthreads();
    for (int s = 128; s > 0; s >>= 1) { if (tid < s) red[tid] += red[tid + s]; __syncthreads(); }
    const float mu = red[0] * (1.f / CH); __syncthreads();
    const float d0 = v0 - mu, d1 = v1 - mu;
    red[tid] = d0 * d0 + d1 * d1; __syncthreads();
    for (int s = 128; s > 0; s >>= 1) { if (tid < s) red[tid] += red[tid + s]; __syncthreads(); }
    const float rs = rsqrtf(red[0] * (1.f / CH) + LN_EPS);
    sattn[b * CH + tid]       = sigmoidf_(d0 * rs);
    sattn[b * CH + tid + 256] = sigmoidf_(d1 * rs);
}

// out = x * (1 + attn); attn = c<512 ? sa[c]*cs[n] : sa[c-512]+cs[n]
__global__ __launch_bounds__(256) void final_k(const float* __restrict__ x,
                                               const float* __restrict__ sattn,
                                               const float* __restrict__ cattnp,
                                               float* __restrict__ out)
{
    const int c = blockIdx.x;
    const int b = blockIdx.y;
    const float s = sattn[b * CH + (c & (CH - 1))];
    const bool seq = c < CH;
    const float4* xr = (const float4*)(x + ((size_t)b * CIN + c) * HW);
    const float4* cr = (const float4*)(cattnp + (size_t)b * HW);
    float4* orow = (float4*)(out + ((size_t)b * CIN + c) * HW);
    for (int i = threadIdx.x; i < HW / 4; i += 256) {
        const float4 xv = xr[i], cv = cr[i];
        float4 f;
        if (seq) { f.x = s * cv.x; f.y = s * cv.y; f.z = s * cv.z; f.w = s * cv.w; }
        else     { f.x = s + cv.x; f.y = s + cv.y; f.z = s + cv.z; f.w = s + cv.w; }
        float4 o;
        o.x = fmaf(xv.x, f.x, xv.x);
        o.y = fmaf(xv.y, f.y, xv.y);
        o.z = fmaf(xv.z, f.z, xv.z);
        o.w = fmaf(xv.w, f.w, xv.w);
        orow[i] = o;
    }
}

extern "C" void kernel_launch(void* const* d_in, const int* in_sizes, int n_in,
                              void* d_out, int out_size, void* d_ws, size_t ws_size,
                              hipStream_t stream)
{
    const float* x    = (const float*)d_in[0];
    const float* w_qr = (const float*)d_in[1];
    const float* w_vr = (const float*)d_in[2];
    const float* w_ql = (const float*)d_in[3];
    const float* w_vl = (const float*)d_in[4];
    float* out = (float*)d_out;

    // big scratch carved out of d_out; all consumed before final_k writes
    unsigned short* xt = (unsigned short*)d_out;             // [b][n][c] bf16, 134 MB
    unsigned short* wA = xt + (size_t)BATCH * HW * CIN;      // 1024*1024 bf16 (ql|vr)
    unsigned short* wB = wA + 1024 * CIN;                    // 512*1024 bf16 (vl)

    float* ws     = (float*)d_ws;
    float* maskp  = ws;                      // 16*4096 raw w_qr sums
    float* gmean  = maskp + BATCH * HW;      // 16*512
    float* ctx    = gmean + BATCH * CH;      // 16*512 (unnormalized ctxu)
    float* cattnp = ctx   + BATCH * CH;      // 16*4096
    float* avgx   = cattnp + BATCH * HW;     // 16*512
    float* sattn  = avgx  + BATCH * CH;      // 16*512
    float* sden   = sattn + BATCH * CH;      // 16

    // zero atomic targets: maskp, gmean, ctx, cattnp (contiguous)
    hipMemsetAsync(maskp, 0,
                   (size_t)(BATCH * HW * 2 + BATCH * CH * 2) * sizeof(float), stream);

    // prep: 16384 transpose blocks + 6144 weight-convert blocks
    prep_k<<<22528, 256, 0, stream>>>(x, w_qr, w_vr, w_ql, w_vl, xt, maskp, wA, wB);

    // GEMM-A: 256 persistent blocks x 4 tiles (ql -> gmean; vr -> ctxu)
    mfma_gemm256<<<256, 512, 0, stream>>>(
        xt, wA, 4, 0, maskp, nullptr, gmean, ctx, nullptr);
    // channel softmax + spatial softmax denominator (one launch)
    smch_S_k<<<32, 256, 0, stream>>>(gmean, maskp, avgx, sden);
    // GEMM-B: 256 persistent blocks x 2 tiles (vl -> cattnp)
    mfma_gemm256<<<256, 512, 0, stream>>>(
        xt, wB, 2, 1, nullptr, avgx, nullptr, nullptr, cattnp);
    // LN(ctxu/S)+sigmoid and sigmoid(cattnp) (one launch)
    lnsig_k<<<272, 256, 0, stream>>>(ctx, sden, sattn, cattnp);
    final_k<<<dim3(CIN, BATCH), 256, 0, stream>>>(x, sattn, cattnp, out);
}